// Round 1
// baseline (549.492 us; speedup 1.0000x reference)
//
#include <hip/hip_runtime.h>
#include <math.h>

#define NEGV (-1000000000.0f)
constexpr int Bb = 8, Ll = 4096, Hh = 512, Cc = 64, Aa = 512;

// ---------------------------------------------------------------------------
// K0: logits[b][l] = tanh(h @ proj_w + pb) @ score_w + sb + log1p(max(cnt,0))
// Also per-batch atomicMax of count into cmax.
// Grid: 1024 blocks (8 b * 128 ltiles of 32 tokens), 256 threads.
// Per-wave: token group of 8 (tg = wave id); per-thread: 8 a-values (a=at*8..+7).
// ---------------------------------------------------------------------------
__global__ __launch_bounds__(256, 2) void k0_logits(
    const float* __restrict__ hid, const float* __restrict__ pw,
    const float* __restrict__ pb, const float* __restrict__ sw,
    const float* __restrict__ sb, const int* __restrict__ cnt,
    float* __restrict__ logits, int* __restrict__ cmax) {
  __shared__ float hs[32 * 512];  // 64 KiB, [token][k]
  const int bid = blockIdx.x;
  const int b = bid >> 7;          // /128
  const int l0 = (bid & 127) * 32;
  const int tid = threadIdx.x;

  const float* hbase = hid + ((size_t)(b * Ll + l0)) * Hh;
#pragma unroll
  for (int i = 0; i < 16; ++i) {
    int q = tid + i * 256;  // float4 index 0..4095
    ((float4*)hs)[q] = ((const float4*)hbase)[q];
  }
  __syncthreads();

  const int tg = tid >> 6;   // wave id = token group
  const int at = tid & 63;   // a-thread
  const int a0 = at * 8;

  float acc[8][8];
#pragma unroll
  for (int t = 0; t < 8; ++t)
#pragma unroll
    for (int u = 0; u < 8; ++u) acc[t][u] = 0.f;

  for (int kb = 0; kb < 128; ++kb) {
    float4 h4[8];
#pragma unroll
    for (int t = 0; t < 8; ++t)
      h4[t] = ((const float4*)hs)[(tg * 8 + t) * 128 + kb];
#pragma unroll
    for (int j = 0; j < 4; ++j) {
      const int k = kb * 4 + j;
      float4 wA = *(const float4*)(pw + (size_t)k * Aa + a0);
      float4 wB = *(const float4*)(pw + (size_t)k * Aa + a0 + 4);
      float wv[8] = {wA.x, wA.y, wA.z, wA.w, wB.x, wB.y, wB.z, wB.w};
#pragma unroll
      for (int t = 0; t < 8; ++t) {
        float hc[4] = {h4[t].x, h4[t].y, h4[t].z, h4[t].w};
        float hk = hc[j];
#pragma unroll
        for (int u = 0; u < 8; ++u) acc[t][u] = fmaf(hk, wv[u], acc[t][u]);
      }
    }
  }

  float4 pA = *(const float4*)(pb + a0);
  float4 pB = *(const float4*)(pb + a0 + 4);
  float4 sA = *(const float4*)(sw + a0);
  float4 sB = *(const float4*)(sw + a0 + 4);
  float pv[8] = {pA.x, pA.y, pA.z, pA.w, pB.x, pB.y, pB.z, pB.w};
  float sv[8] = {sA.x, sA.y, sA.z, sA.w, sB.x, sB.y, sB.z, sB.w};

  float local[8];
#pragma unroll
  for (int t = 0; t < 8; ++t) {
    float s = 0.f;
#pragma unroll
    for (int u = 0; u < 8; ++u) s += tanhf(acc[t][u] + pv[u]) * sv[u];
    local[t] = s;
  }
#pragma unroll
  for (int m = 32; m >= 1; m >>= 1) {
#pragma unroll
    for (int t = 0; t < 8; ++t) local[t] += __shfl_xor(local[t], m);
  }
  if (at == 0) {
    float sbv = sb[0];
#pragma unroll
    for (int t = 0; t < 8; ++t) {
      int l = l0 + tg * 8 + t;
      float cf = (float)cnt[b * Ll + l];
      logits[b * Ll + l] = local[t] + sbv + log1pf(fmaxf(cf, 0.f));
    }
  }
  if (tid < 32) atomicMax(&cmax[b], cnt[b * Ll + l0 + tid]);
}

// ---------------------------------------------------------------------------
// K2: actT[b][c][l] = relu(act[b][l][c]);  dinv[b][l] = 1/max(sum_c relu, 1)
// Grid: 512 blocks (8 b * 64 ltiles of 64), 256 threads.
// ---------------------------------------------------------------------------
__global__ void k2_transpose(const float* __restrict__ act,
                             float* __restrict__ actT,
                             float* __restrict__ dinv) {
  __shared__ float t64[64][65];
  const int b = blockIdx.x >> 6;
  const int l0 = (blockIdx.x & 63) * 64;
  const int tid = threadIdx.x;
#pragma unroll
  for (int i = 0; i < 16; ++i) {
    int e = tid + i * 256;
    int l = e >> 6, c = e & 63;
    float v = act[((size_t)(b * Ll + l0 + l)) * Cc + c];
    t64[l][c] = fmaxf(v, 0.f);
  }
  __syncthreads();
  if (tid < 64) {
    float s = 0.f;
#pragma unroll 8
    for (int c = 0; c < 64; ++c) s += t64[tid][c];
    dinv[b * Ll + l0 + tid] = 1.0f / fmaxf(s, 1.0f);
  }
#pragma unroll
  for (int i = 0; i < 16; ++i) {
    int e = tid + i * 256;
    int c = e >> 6, lq = e & 63;
    actT[((size_t)(b * Cc + c)) * Ll + l0 + lq] = t64[lq][c];
  }
}

// ---------------------------------------------------------------------------
// K3: per (b,c) row: masked log1p logits -> softmax over L -> weights output.
// Grid: 512 blocks (= b*64+c), 256 threads, 16 elements each (in registers).
// ---------------------------------------------------------------------------
__global__ void k3_softmax(const float* __restrict__ actT,
                           const float* __restrict__ logits,
                           float* __restrict__ wout,
                           int* __restrict__ hasany) {
  __shared__ float rmax[4], rcnt[4], rsum[4];
  const int bid = blockIdx.x;  // b*64+c
  const int b = bid >> 6;
  const int tid = threadIdx.x;
  const float* arow = actT + (size_t)bid * Ll;

  float xs[16];
  float lmax = NEGV, fcnt = 0.f;
#pragma unroll
  for (int i = 0; i < 16; ++i) {
    int l = tid + i * 256;
    float a = arow[l];
    float x;
    if (a > 0.f) {
      x = logits[b * Ll + l] + log1pf(a);
      fcnt += 1.f;
    } else {
      x = NEGV;
    }
    xs[i] = x;
    lmax = fmaxf(lmax, x);
  }
#pragma unroll
  for (int m = 32; m >= 1; m >>= 1) {
    lmax = fmaxf(lmax, __shfl_xor(lmax, m));
    fcnt += __shfl_xor(fcnt, m);
  }
  if ((tid & 63) == 0) { rmax[tid >> 6] = lmax; rcnt[tid >> 6] = fcnt; }
  __syncthreads();
  float m4 = fmaxf(fmaxf(rmax[0], rmax[1]), fmaxf(rmax[2], rmax[3]));
  float call = rcnt[0] + rcnt[1] + rcnt[2] + rcnt[3];

  float lsum = 0.f;
#pragma unroll
  for (int i = 0; i < 16; ++i) {
    float e = expf(xs[i] - m4);
    xs[i] = e;
    lsum += e;
  }
#pragma unroll
  for (int m = 32; m >= 1; m >>= 1) lsum += __shfl_xor(lsum, m);
  if ((tid & 63) == 0) rsum[tid >> 6] = lsum;
  __syncthreads();
  float s = rsum[0] + rsum[1] + rsum[2] + rsum[3];
  int any = call > 0.5f;
  float inv = any ? 1.0f / s : 0.f;
#pragma unroll
  for (int i = 0; i < 16; ++i)
    wout[(size_t)bid * Ll + tid + i * 256] = xs[i] * inv;
  if (tid == 0) hasany[bid] = any;
}

// ---------------------------------------------------------------------------
// K5: cctx[b][c][h] += sum_l w[b][c][l] * hid[b][l][h]  (partial over l-chunk)
// Grid: (8 b, 4 htiles of 128, 16 lchunks of 256), 256 threads.
// Thread tile: 4 c (tc, tc+16, tc+32, tc+48) x 8 h.
// ---------------------------------------------------------------------------
__global__ __launch_bounds__(256, 2) void k5_ctx(
    const float* __restrict__ hid, const float* __restrict__ wout,
    float* __restrict__ cctx) {
  __shared__ float wtile[64 * 36];   // [c][l], stride 36 (16B aligned rows)
  __shared__ float htile[32 * 132];  // [l][h], stride 132
  const int b = blockIdx.x, ht = blockIdx.y, lz = blockIdx.z;
  const int h0 = ht * 128;
  const int tid = threadIdx.x;
  const int tc = tid & 15, th = tid >> 4;

  float acc[4][8];
#pragma unroll
  for (int i = 0; i < 4; ++i)
#pragma unroll
    for (int u = 0; u < 8; ++u) acc[i][u] = 0.f;

  for (int ls = 0; ls < 8; ++ls) {
    const int l0 = lz * 256 + ls * 32;
    __syncthreads();
#pragma unroll
    for (int i = 0; i < 2; ++i) {
      int q = tid + i * 256;  // 0..511
      int c = q >> 3, lq = q & 7;
      float4 w4 = *(const float4*)(wout + ((size_t)(b * Cc + c)) * Ll + l0 + lq * 4);
      *(float4*)(wtile + c * 36 + lq * 4) = w4;
    }
#pragma unroll
    for (int i = 0; i < 4; ++i) {
      int q = tid + i * 256;  // 0..1023
      int l = q >> 5, hq = q & 31;
      float4 h4 = *(const float4*)(hid + ((size_t)(b * Ll + l0 + l)) * Hh + h0 + hq * 4);
      *(float4*)(htile + l * 132 + hq * 4) = h4;
    }
    __syncthreads();
#pragma unroll 4
    for (int l = 0; l < 32; ++l) {
      float4 hA = *(const float4*)(htile + l * 132 + th * 8);
      float4 hB = *(const float4*)(htile + l * 132 + th * 8 + 4);
      float hv[8] = {hA.x, hA.y, hA.z, hA.w, hB.x, hB.y, hB.z, hB.w};
#pragma unroll
      for (int i = 0; i < 4; ++i) {
        float w = wtile[(tc + 16 * i) * 36 + l];
#pragma unroll
        for (int u = 0; u < 8; ++u) acc[i][u] = fmaf(w, hv[u], acc[i][u]);
      }
    }
  }
#pragma unroll
  for (int i = 0; i < 4; ++i)
#pragma unroll
    for (int u = 0; u < 8; ++u)
      atomicAdd(&cctx[((size_t)(b * Cc + tc + 16 * i)) * Hh + h0 + th * 8 + u],
                acc[i][u]);
}

// ---------------------------------------------------------------------------
// K6: fallback: where !hasany, cctx[b][c][:] = hid[b][L-1][:]
// ---------------------------------------------------------------------------
__global__ void k6_fallback(float* __restrict__ cctx,
                            const int* __restrict__ hasany,
                            const float* __restrict__ hid) {
  int idx = blockIdx.x * 256 + threadIdx.x;  // 0..262143
  int bc = idx >> 9;
  int h = idx & 511;
  int b = bc >> 6;
  if (!hasany[bc]) cctx[idx] = hid[((size_t)(b * Ll + (Ll - 1))) * Hh + h];
}

// ---------------------------------------------------------------------------
// K7: attended = mask ? (mix @ cctx) * gate : hidden
// Grid: (8 b, 128 ltiles of 32), 256 threads. Per-wave 8 tokens, per-thread 8 h.
// ---------------------------------------------------------------------------
__global__ __launch_bounds__(256, 2) void k7_out(
    const float* __restrict__ hid, const float* __restrict__ act,
    const float* __restrict__ dinv, const float* __restrict__ cctx,
    const int* __restrict__ mask, const int* __restrict__ cnt,
    const int* __restrict__ cmax, float* __restrict__ out) {
  __shared__ float mix[32 * 68];  // [token][c], stride 68 (16B aligned)
  __shared__ float gateb[32];
  __shared__ int maskb[32];
  const int b = blockIdx.x;
  const int l0 = blockIdx.y * 32;
  const int tid = threadIdx.x;
  const float maxcf = fmaxf((float)cmax[b], 1.0f);

#pragma unroll
  for (int i = 0; i < 2; ++i) {
    int q = tid + i * 256;  // 0..511
    int t = q >> 4, cq = q & 15;
    float4 a4 = *(const float4*)(act + ((size_t)(b * Ll + l0 + t)) * Cc + cq * 4);
    float dv = dinv[b * Ll + l0 + t];
    a4.x = fmaxf(a4.x, 0.f) * dv;
    a4.y = fmaxf(a4.y, 0.f) * dv;
    a4.z = fmaxf(a4.z, 0.f) * dv;
    a4.w = fmaxf(a4.w, 0.f) * dv;
    *(float4*)(mix + t * 68 + cq * 4) = a4;
  }
  if (tid < 32) {
    int l = l0 + tid;
    maskb[tid] = mask[b * Ll + l];
    gateb[tid] = 1.0f + (float)cnt[b * Ll + l] / maxcf;
  }
  __syncthreads();

  const int tt = tid >> 6;
  const int h = (tid & 63) * 8;
  float acc[8][8];
#pragma unroll
  for (int t = 0; t < 8; ++t)
#pragma unroll
    for (int u = 0; u < 8; ++u) acc[t][u] = 0.f;

#pragma unroll 4
  for (int c = 0; c < 64; ++c) {
    float4 cA = *(const float4*)(cctx + ((size_t)(b * Cc + c)) * Hh + h);
    float4 cB = *(const float4*)(cctx + ((size_t)(b * Cc + c)) * Hh + h + 4);
    float cv[8] = {cA.x, cA.y, cA.z, cA.w, cB.x, cB.y, cB.z, cB.w};
#pragma unroll
    for (int t = 0; t < 8; ++t) {
      float mv = mix[(tt * 8 + t) * 68 + c];
#pragma unroll
      for (int u = 0; u < 8; ++u) acc[t][u] = fmaf(mv, cv[u], acc[t][u]);
    }
  }
#pragma unroll
  for (int t = 0; t < 8; ++t) {
    int tok = tt * 8 + t;
    size_t off = ((size_t)(b * Ll + l0 + tok)) * Hh + h;
    float4 o1, o2;
    if (maskb[tok]) {
      float g = gateb[tok];
      o1 = make_float4(acc[t][0] * g, acc[t][1] * g, acc[t][2] * g, acc[t][3] * g);
      o2 = make_float4(acc[t][4] * g, acc[t][5] * g, acc[t][6] * g, acc[t][7] * g);
    } else {
      o1 = *(const float4*)(hid + off);
      o2 = *(const float4*)(hid + off + 4);
    }
    *(float4*)(out + off) = o1;
    *(float4*)(out + off + 4) = o2;
  }
}

// ---------------------------------------------------------------------------
extern "C" void kernel_launch(void* const* d_in, const int* in_sizes, int n_in,
                              void* d_out, int out_size, void* d_ws,
                              size_t ws_size, hipStream_t stream) {
  const float* hid = (const float*)d_in[0];
  const int* mask = (const int*)d_in[1];
  const int* cnt = (const int*)d_in[2];
  const float* act = (const float*)d_in[3];
  const float* pw = (const float*)d_in[4];
  const float* pb = (const float*)d_in[5];
  const float* sw = (const float*)d_in[6];
  const float* sb = (const float*)d_in[7];

  float* out_att = (float*)d_out;                       // (B,L,H)
  float* out_w = out_att + (size_t)Bb * Ll * Hh;        // (B,C,L)

  float* ws = (float*)d_ws;
  float* cctx = ws;                                     // 262144 f
  int* cmaxi = (int*)(ws + 262144);                     // 8 i
  float* logits = ws + 262144 + 8;                      // 32768 f
  float* actT = logits + 32768;                         // 2097152 f
  float* dinv = actT + 2097152;                         // 32768 f
  int* hasany = (int*)(dinv + 32768);                   // 512 i

  hipMemsetAsync(cctx, 0, (262144 + 8) * sizeof(float), stream);

  k0_logits<<<1024, 256, 0, stream>>>(hid, pw, pb, sw, sb, cnt, logits, cmaxi);
  k2_transpose<<<512, 256, 0, stream>>>(act, actT, dinv);
  k3_softmax<<<512, 256, 0, stream>>>(actT, logits, out_w, hasany);
  k5_ctx<<<dim3(8, 4, 16), 256, 0, stream>>>(hid, out_w, cctx);
  k6_fallback<<<1024, 256, 0, stream>>>(cctx, hasany, hid);
  k7_out<<<dim3(8, 128), 256, 0, stream>>>(hid, act, dinv, cctx, mask, cnt,
                                           cmaxi, out_att);
}

// Round 2
// 382.314 us; speedup vs baseline: 1.4373x; 1.4373x over previous
//
#include <hip/hip_runtime.h>
#include <hip/hip_bf16.h>
#include <math.h>

#define NEGV (-1000000000.0f)
constexpr int Bb = 8, Ll = 4096, Hh = 512, Cc = 64, Aa = 512;

typedef float f32x4 __attribute__((ext_vector_type(4)));
typedef short s16x8 __attribute__((ext_vector_type(8)));

__device__ inline ushort f2bf(float f) {
  union { float f; uint u; } v; v.f = f;
  uint u = v.u;
  return (ushort)((u + 0x7FFFu + ((u >> 16) & 1u)) >> 16);
}

__device__ inline uint bfpack2(float x, float y) {
  __hip_bfloat162 h = __float22bfloat162_rn(make_float2(x, y));
  union { __hip_bfloat162 h; uint u; } v; v.h = h;
  return v.u;
}

// ---------------------------------------------------------------------------
// k_init: logits[b][l] = sb + log1p(max(cnt,0));  cmax[b] = max count.
// ---------------------------------------------------------------------------
__global__ void k_init(const int* __restrict__ cnt, const float* __restrict__ sb,
                       float* __restrict__ logits, int* __restrict__ cmax) {
  int i = blockIdx.x * 256 + threadIdx.x;  // 0..32767
  int c = cnt[i];
  logits[i] = sb[0] + log1pf(fmaxf((float)c, 0.f));
  int m = c;
#pragma unroll
  for (int s = 32; s; s >>= 1) m = max(m, __shfl_xor(m, s));
  if ((threadIdx.x & 63) == 0) atomicMax(&cmax[i >> 12], m);
}

// ---------------------------------------------------------------------------
// kT_pw: pwT[a][k] = bf16(pw[k][a]).  Grid 64 blocks (8 ktiles x 8 atiles).
// ---------------------------------------------------------------------------
__global__ void kT_pw(const float* __restrict__ pw, ushort* __restrict__ pwT) {
  __shared__ ushort s[64][65];
  const int k0 = (blockIdx.x >> 3) * 64, a0 = (blockIdx.x & 7) * 64;
  const int t = threadIdx.x;
#pragma unroll
  for (int i = 0; i < 16; ++i) {
    int e = t + i * 256;
    int kk = e >> 6, aa = e & 63;
    s[aa][kk] = f2bf(pw[(size_t)(k0 + kk) * Aa + a0 + aa]);
  }
  __syncthreads();
#pragma unroll
  for (int i = 0; i < 16; ++i) {
    int e = t + i * 256;
    int aa = e >> 6, kk = e & 63;
    pwT[(size_t)(a0 + aa) * Hh + k0 + kk] = s[aa][kk];
  }
}

// ---------------------------------------------------------------------------
// k0_gemm: logits += sum_a tanh((hid @ pw)[m][a] + pb[a]) * sw[a]
// bf16 MFMA 16x16x32, 128x128 block tile, BK=32, fp32->bf16 fused in staging.
// Grid (256 m-tiles, 4 n-tiles), 256 threads (4 waves, 2x2 wave grid).
// ---------------------------------------------------------------------------
__global__ __launch_bounds__(256) void k0_gemm(
    const float* __restrict__ hid, const ushort* __restrict__ pwT,
    const float* __restrict__ pb, const float* __restrict__ sw,
    float* __restrict__ logits) {
  __shared__ ushort At[128 * 40];  // [row][k] stride 40 bf16 (80 B)
  __shared__ ushort Bt[128 * 40];  // [n][k]
  const int bm = blockIdx.x, bn = blockIdx.y;
  const int tid = threadIdx.x;
  const int lane = tid & 63;
  const int w = tid >> 6;
  const int wm = w >> 1, wn = w & 1;
  const int lc = lane & 15, lq = lane >> 4;

  // staging assignment: thread -> (row, k-half)
  const int sr = tid >> 1;
  const int sk = (tid & 1) * 16;  // in elements

  const float* Ag = hid + ((size_t)(bm * 128 + sr)) * Hh + sk;
  const ushort* Bg = pwT + ((size_t)(bn * 128 + sr)) * Hh + sk;

  f32x4 acc[4][4];
#pragma unroll
  for (int mi = 0; mi < 4; ++mi)
#pragma unroll
    for (int ni = 0; ni < 4; ++ni) acc[mi][ni] = (f32x4){0.f, 0.f, 0.f, 0.f};

  // fragment LDS offsets (ushort units), fixed across K-loop
  int aoff[4], boff[4];
#pragma unroll
  for (int i = 0; i < 4; ++i) {
    aoff[i] = (wm * 64 + i * 16 + lc) * 40 + lq * 8;
    boff[i] = (wn * 64 + i * 16 + lc) * 40 + lq * 8;
  }

  // prefetch kb=0
  float4 a0 = *(const float4*)(Ag + 0), a1 = *(const float4*)(Ag + 4),
         a2 = *(const float4*)(Ag + 8), a3 = *(const float4*)(Ag + 12);
  uint4 b0 = *(const uint4*)(Bg + 0), b1 = *(const uint4*)(Bg + 8);

  for (int kb = 0; kb < 16; ++kb) {
    __syncthreads();
    uint4 p0 = {bfpack2(a0.x, a0.y), bfpack2(a0.z, a0.w),
                bfpack2(a1.x, a1.y), bfpack2(a1.z, a1.w)};
    uint4 p1 = {bfpack2(a2.x, a2.y), bfpack2(a2.z, a2.w),
                bfpack2(a3.x, a3.y), bfpack2(a3.z, a3.w)};
    *(uint4*)(At + sr * 40 + sk) = p0;
    *(uint4*)(At + sr * 40 + sk + 8) = p1;
    *(uint4*)(Bt + sr * 40 + sk) = b0;
    *(uint4*)(Bt + sr * 40 + sk + 8) = b1;
    __syncthreads();
    if (kb < 15) {
      const float* ag = Ag + (kb + 1) * 32;
      const ushort* bg = Bg + (kb + 1) * 32;
      a0 = *(const float4*)(ag + 0); a1 = *(const float4*)(ag + 4);
      a2 = *(const float4*)(ag + 8); a3 = *(const float4*)(ag + 12);
      b0 = *(const uint4*)(bg + 0); b1 = *(const uint4*)(bg + 8);
    }
    s16x8 af[4], bf[4];
#pragma unroll
    for (int mi = 0; mi < 4; ++mi) af[mi] = *(const s16x8*)(At + aoff[mi]);
#pragma unroll
    for (int ni = 0; ni < 4; ++ni) bf[ni] = *(const s16x8*)(Bt + boff[ni]);
#pragma unroll
    for (int mi = 0; mi < 4; ++mi)
#pragma unroll
      for (int ni = 0; ni < 4; ++ni)
        acc[mi][ni] = __builtin_amdgcn_mfma_f32_16x16x32_bf16(
            af[mi], bf[ni], acc[mi][ni], 0, 0, 0);
  }

  // epilogue: tanh(x + pb[n]) * sw[n], reduce over n, atomicAdd into logits
  float pbv[4], swv[4];
#pragma unroll
  for (int ni = 0; ni < 4; ++ni) {
    int n = bn * 128 + wn * 64 + ni * 16 + lc;
    pbv[ni] = pb[n];
    swv[ni] = sw[n];
  }
#pragma unroll
  for (int mi = 0; mi < 4; ++mi) {
#pragma unroll
    for (int r = 0; r < 4; ++r) {
      float s = 0.f;
#pragma unroll
      for (int ni = 0; ni < 4; ++ni) {
        float x = acc[mi][ni][r] + pbv[ni];
        float e = __expf(2.f * x);
        float th = 1.f - 2.f / (e + 1.f);
        s = fmaf(th, swv[ni], s);
      }
      s += __shfl_xor(s, 1);
      s += __shfl_xor(s, 2);
      s += __shfl_xor(s, 4);
      s += __shfl_xor(s, 8);
      if (lc == 0) {
        int m = bm * 128 + wm * 64 + mi * 16 + lq * 4 + r;
        atomicAdd(&logits[m], s);
      }
    }
  }
}

// ---------------------------------------------------------------------------
// K2: actT[b][c][l] = relu(act[b][l][c]);  dinv[b][l] = 1/max(sum_c relu, 1)
// ---------------------------------------------------------------------------
__global__ void k2_transpose(const float* __restrict__ act,
                             float* __restrict__ actT,
                             float* __restrict__ dinv) {
  __shared__ float t64[64][65];
  const int b = blockIdx.x >> 6;
  const int l0 = (blockIdx.x & 63) * 64;
  const int tid = threadIdx.x;
#pragma unroll
  for (int i = 0; i < 16; ++i) {
    int e = tid + i * 256;
    int l = e >> 6, c = e & 63;
    float v = act[((size_t)(b * Ll + l0 + l)) * Cc + c];
    t64[l][c] = fmaxf(v, 0.f);
  }
  __syncthreads();
  if (tid < 64) {
    float s = 0.f;
#pragma unroll 8
    for (int c = 0; c < 64; ++c) s += t64[tid][c];
    dinv[b * Ll + l0 + tid] = 1.0f / fmaxf(s, 1.0f);
  }
#pragma unroll
  for (int i = 0; i < 16; ++i) {
    int e = tid + i * 256;
    int c = e >> 6, lq = e & 63;
    actT[((size_t)(b * Cc + c)) * Ll + l0 + lq] = t64[lq][c];
  }
}

// ---------------------------------------------------------------------------
// K3: per (b,c) row: masked log1p logits -> softmax over L -> weights output.
// ---------------------------------------------------------------------------
__global__ void k3_softmax(const float* __restrict__ actT,
                           const float* __restrict__ logits,
                           float* __restrict__ wout,
                           int* __restrict__ hasany) {
  __shared__ float rmax[4], rcnt[4], rsum[4];
  const int bid = blockIdx.x;  // b*64+c
  const int b = bid >> 6;
  const int tid = threadIdx.x;
  const float* arow = actT + (size_t)bid * Ll;

  float xs[16];
  float lmax = NEGV, fcnt = 0.f;
#pragma unroll
  for (int i = 0; i < 16; ++i) {
    int l = tid + i * 256;
    float a = arow[l];
    float x;
    if (a > 0.f) {
      x = logits[b * Ll + l] + log1pf(a);
      fcnt += 1.f;
    } else {
      x = NEGV;
    }
    xs[i] = x;
    lmax = fmaxf(lmax, x);
  }
#pragma unroll
  for (int m = 32; m >= 1; m >>= 1) {
    lmax = fmaxf(lmax, __shfl_xor(lmax, m));
    fcnt += __shfl_xor(fcnt, m);
  }
  if ((tid & 63) == 0) { rmax[tid >> 6] = lmax; rcnt[tid >> 6] = fcnt; }
  __syncthreads();
  float m4 = fmaxf(fmaxf(rmax[0], rmax[1]), fmaxf(rmax[2], rmax[3]));
  float call = rcnt[0] + rcnt[1] + rcnt[2] + rcnt[3];

  float lsum = 0.f;
#pragma unroll
  for (int i = 0; i < 16; ++i) {
    float e = expf(xs[i] - m4);
    xs[i] = e;
    lsum += e;
  }
#pragma unroll
  for (int m = 32; m >= 1; m >>= 1) lsum += __shfl_xor(lsum, m);
  if ((tid & 63) == 0) rsum[tid >> 6] = lsum;
  __syncthreads();
  float s = rsum[0] + rsum[1] + rsum[2] + rsum[3];
  int any = call > 0.5f;
  float inv = any ? 1.0f / s : 0.f;
#pragma unroll
  for (int i = 0; i < 16; ++i)
    wout[(size_t)bid * Ll + tid + i * 256] = xs[i] * inv;
  if (tid == 0) hasany[bid] = any;
}

// ---------------------------------------------------------------------------
// K5: cctx[b][c][h] += sum_l w[b][c][l] * hid[b][l][h]  (partial over l-chunk)
// ---------------------------------------------------------------------------
__global__ __launch_bounds__(256, 2) void k5_ctx(
    const float* __restrict__ hid, const float* __restrict__ wout,
    float* __restrict__ cctx) {
  __shared__ float wtile[64 * 36];
  __shared__ float htile[32 * 132];
  const int b = blockIdx.x, ht = blockIdx.y, lz = blockIdx.z;
  const int h0 = ht * 128;
  const int tid = threadIdx.x;
  const int tc = tid & 15, th = tid >> 4;

  float acc[4][8];
#pragma unroll
  for (int i = 0; i < 4; ++i)
#pragma unroll
    for (int u = 0; u < 8; ++u) acc[i][u] = 0.f;

  for (int ls = 0; ls < 8; ++ls) {
    const int l0 = lz * 256 + ls * 32;
    __syncthreads();
#pragma unroll
    for (int i = 0; i < 2; ++i) {
      int q = tid + i * 256;
      int c = q >> 3, lq = q & 7;
      float4 w4 = *(const float4*)(wout + ((size_t)(b * Cc + c)) * Ll + l0 + lq * 4);
      *(float4*)(wtile + c * 36 + lq * 4) = w4;
    }
#pragma unroll
    for (int i = 0; i < 4; ++i) {
      int q = tid + i * 256;
      int l = q >> 5, hq = q & 31;
      float4 h4 = *(const float4*)(hid + ((size_t)(b * Ll + l0 + l)) * Hh + h0 + hq * 4);
      *(float4*)(htile + l * 132 + hq * 4) = h4;
    }
    __syncthreads();
#pragma unroll 4
    for (int l = 0; l < 32; ++l) {
      float4 hA = *(const float4*)(htile + l * 132 + th * 8);
      float4 hB = *(const float4*)(htile + l * 132 + th * 8 + 4);
      float hv[8] = {hA.x, hA.y, hA.z, hA.w, hB.x, hB.y, hB.z, hB.w};
#pragma unroll
      for (int i = 0; i < 4; ++i) {
        float w = wtile[(tc + 16 * i) * 36 + l];
#pragma unroll
        for (int u = 0; u < 8; ++u) acc[i][u] = fmaf(w, hv[u], acc[i][u]);
      }
    }
  }
#pragma unroll
  for (int i = 0; i < 4; ++i)
#pragma unroll
    for (int u = 0; u < 8; ++u)
      atomicAdd(&cctx[((size_t)(b * Cc + tc + 16 * i)) * Hh + h0 + th * 8 + u],
                acc[i][u]);
}

// ---------------------------------------------------------------------------
// K6: fallback: where !hasany, cctx[b][c][:] = hid[b][L-1][:]
// ---------------------------------------------------------------------------
__global__ void k6_fallback(float* __restrict__ cctx,
                            const int* __restrict__ hasany,
                            const float* __restrict__ hid) {
  int idx = blockIdx.x * 256 + threadIdx.x;
  int bc = idx >> 9;
  int h = idx & 511;
  int b = bc >> 6;
  if (!hasany[bc]) cctx[idx] = hid[((size_t)(b * Ll + (Ll - 1))) * Hh + h];
}

// ---------------------------------------------------------------------------
// K7: attended = mask ? (mix @ cctx) * gate : hidden
// ---------------------------------------------------------------------------
__global__ __launch_bounds__(256, 2) void k7_out(
    const float* __restrict__ hid, const float* __restrict__ act,
    const float* __restrict__ dinv, const float* __restrict__ cctx,
    const int* __restrict__ mask, const int* __restrict__ cnt,
    const int* __restrict__ cmax, float* __restrict__ out) {
  __shared__ float mix[32 * 68];
  __shared__ float gateb[32];
  __shared__ int maskb[32];
  const int b = blockIdx.x;
  const int l0 = blockIdx.y * 32;
  const int tid = threadIdx.x;
  const float maxcf = fmaxf((float)cmax[b], 1.0f);

#pragma unroll
  for (int i = 0; i < 2; ++i) {
    int q = tid + i * 256;
    int t = q >> 4, cq = q & 15;
    float4 a4 = *(const float4*)(act + ((size_t)(b * Ll + l0 + t)) * Cc + cq * 4);
    float dv = dinv[b * Ll + l0 + t];
    a4.x = fmaxf(a4.x, 0.f) * dv;
    a4.y = fmaxf(a4.y, 0.f) * dv;
    a4.z = fmaxf(a4.z, 0.f) * dv;
    a4.w = fmaxf(a4.w, 0.f) * dv;
    *(float4*)(mix + t * 68 + cq * 4) = a4;
  }
  if (tid < 32) {
    int l = l0 + tid;
    maskb[tid] = mask[b * Ll + l];
    gateb[tid] = 1.0f + (float)cnt[b * Ll + l] / maxcf;
  }
  __syncthreads();

  const int tt = tid >> 6;
  const int h = (tid & 63) * 8;
  float acc[8][8];
#pragma unroll
  for (int t = 0; t < 8; ++t)
#pragma unroll
    for (int u = 0; u < 8; ++u) acc[t][u] = 0.f;

#pragma unroll 4
  for (int c = 0; c < 64; ++c) {
    float4 cA = *(const float4*)(cctx + ((size_t)(b * Cc + c)) * Hh + h);
    float4 cB = *(const float4*)(cctx + ((size_t)(b * Cc + c)) * Hh + h + 4);
    float cv[8] = {cA.x, cA.y, cA.z, cA.w, cB.x, cB.y, cB.z, cB.w};
#pragma unroll
    for (int t = 0; t < 8; ++t) {
      float mv = mix[(tt * 8 + t) * 68 + c];
#pragma unroll
      for (int u = 0; u < 8; ++u) acc[t][u] = fmaf(mv, cv[u], acc[t][u]);
    }
  }
#pragma unroll
  for (int t = 0; t < 8; ++t) {
    int tok = tt * 8 + t;
    size_t off = ((size_t)(b * Ll + l0 + tok)) * Hh + h;
    float4 o1, o2;
    if (maskb[tok]) {
      float g = gateb[tok];
      o1 = make_float4(acc[t][0] * g, acc[t][1] * g, acc[t][2] * g, acc[t][3] * g);
      o2 = make_float4(acc[t][4] * g, acc[t][5] * g, acc[t][6] * g, acc[t][7] * g);
    } else {
      o1 = *(const float4*)(hid + off);
      o2 = *(const float4*)(hid + off + 4);
    }
    *(float4*)(out + off) = o1;
    *(float4*)(out + off + 4) = o2;
  }
}

// ---------------------------------------------------------------------------
extern "C" void kernel_launch(void* const* d_in, const int* in_sizes, int n_in,
                              void* d_out, int out_size, void* d_ws,
                              size_t ws_size, hipStream_t stream) {
  const float* hid = (const float*)d_in[0];
  const int* mask = (const int*)d_in[1];
  const int* cnt = (const int*)d_in[2];
  const float* act = (const float*)d_in[3];
  const float* pw = (const float*)d_in[4];
  const float* pb = (const float*)d_in[5];
  const float* sw = (const float*)d_in[6];
  const float* sb = (const float*)d_in[7];

  float* out_att = (float*)d_out;                 // (B,L,H)
  float* out_w = out_att + (size_t)Bb * Ll * Hh;  // (B,C,L)

  float* ws = (float*)d_ws;
  float* cctx = ws;                               // 262144 f
  int* cmaxi = (int*)(ws + 262144);               // 8 i
  float* logits = ws + 262144 + 8;                // 32768 f
  float* actT = logits + 32768;                   // 2097152 f
  float* dinv = actT + 2097152;                   // 32768 f
  int* hasany = (int*)(dinv + 32768);             // 512 i
  ushort* pwT = (ushort*)(hasany + 512);          // 262144 bf16

  hipMemsetAsync(cctx, 0, (262144 + 8) * sizeof(float), stream);

  k_init<<<128, 256, 0, stream>>>(cnt, sb, logits, cmaxi);
  kT_pw<<<64, 256, 0, stream>>>(pw, pwT);
  k0_gemm<<<dim3(256, 4), 256, 0, stream>>>(hid, pwT, pb, sw, logits);
  k2_transpose<<<512, 256, 0, stream>>>(act, actT, dinv);
  k3_softmax<<<512, 256, 0, stream>>>(actT, logits, out_w, hasany);
  k5_ctx<<<dim3(8, 4, 16), 256, 0, stream>>>(hid, out_w, cctx);
  k6_fallback<<<1024, 256, 0, stream>>>(cctx, hasany, hid);
  k7_out<<<dim3(8, 128), 256, 0, stream>>>(hid, act, dinv, cctx, mask, cnt,
                                           cmaxi, out_att);
}

// Round 3
// 275.115 us; speedup vs baseline: 1.9973x; 1.3896x over previous
//
#include <hip/hip_runtime.h>
#include <hip/hip_bf16.h>
#include <math.h>

#define NEGV (-1000000000.0f)
constexpr int Bb = 8, Ll = 4096, Hh = 512, Cc = 64, Aa = 512;

typedef float f32x4 __attribute__((ext_vector_type(4)));
typedef short s16x8 __attribute__((ext_vector_type(8)));

__device__ inline ushort f2bf(float f) {
  union { float f; uint u; } v; v.f = f;
  uint u = v.u;
  return (ushort)((u + 0x7FFFu + ((u >> 16) & 1u)) >> 16);
}

__device__ inline uint bfpack2(float x, float y) {
  __hip_bfloat162 h = __float22bfloat162_rn(make_float2(x, y));
  union { __hip_bfloat162 h; uint u; } v; v.h = h;
  return v.u;
}

// ---------------------------------------------------------------------------
// k_init: logits[b][l] = sb + log1p(max(cnt,0));  cmax[b] = max count.
// ---------------------------------------------------------------------------
__global__ void k_init(const int* __restrict__ cnt, const float* __restrict__ sb,
                       float* __restrict__ logits, int* __restrict__ cmax) {
  int i = blockIdx.x * 256 + threadIdx.x;  // 0..32767
  int c = cnt[i];
  logits[i] = sb[0] + log1pf(fmaxf((float)c, 0.f));
  int m = c;
#pragma unroll
  for (int s = 32; s; s >>= 1) m = max(m, __shfl_xor(m, s));
  if ((threadIdx.x & 63) == 0) atomicMax(&cmax[i >> 12], m);
}

// ---------------------------------------------------------------------------
// kT_pw: pwT[a][k] = bf16(pw[k][a]).  Grid 64 blocks (8 ktiles x 8 atiles).
// ---------------------------------------------------------------------------
__global__ void kT_pw(const float* __restrict__ pw, ushort* __restrict__ pwT) {
  __shared__ ushort s[64][65];
  const int k0 = (blockIdx.x >> 3) * 64, a0 = (blockIdx.x & 7) * 64;
  const int t = threadIdx.x;
#pragma unroll
  for (int i = 0; i < 16; ++i) {
    int e = t + i * 256;
    int kk = e >> 6, aa = e & 63;
    s[aa][kk] = f2bf(pw[(size_t)(k0 + kk) * Aa + a0 + aa]);
  }
  __syncthreads();
#pragma unroll
  for (int i = 0; i < 16; ++i) {
    int e = t + i * 256;
    int aa = e >> 6, kk = e & 63;
    pwT[(size_t)(a0 + aa) * Hh + k0 + kk] = s[aa][kk];
  }
}

// ---------------------------------------------------------------------------
// k0_gemm: logits += sum_a tanh((hid @ pw)[m][a] + pb[a]) * sw[a]
// bf16 MFMA 16x16x32, 128x128 block tile, BK=32, fp32->bf16 fused in staging.
// ---------------------------------------------------------------------------
__global__ __launch_bounds__(256) void k0_gemm(
    const float* __restrict__ hid, const ushort* __restrict__ pwT,
    const float* __restrict__ pb, const float* __restrict__ sw,
    float* __restrict__ logits) {
  __shared__ ushort At[128 * 40];  // [row][k] stride 40 bf16 (80 B)
  __shared__ ushort Bt[128 * 40];  // [n][k]
  const int bm = blockIdx.x, bn = blockIdx.y;
  const int tid = threadIdx.x;
  const int lane = tid & 63;
  const int w = tid >> 6;
  const int wm = w >> 1, wn = w & 1;
  const int lc = lane & 15, lq = lane >> 4;

  const int sr = tid >> 1;
  const int sk = (tid & 1) * 16;

  const float* Ag = hid + ((size_t)(bm * 128 + sr)) * Hh + sk;
  const ushort* Bg = pwT + ((size_t)(bn * 128 + sr)) * Hh + sk;

  f32x4 acc[4][4];
#pragma unroll
  for (int mi = 0; mi < 4; ++mi)
#pragma unroll
    for (int ni = 0; ni < 4; ++ni) acc[mi][ni] = (f32x4){0.f, 0.f, 0.f, 0.f};

  int aoff[4], boff[4];
#pragma unroll
  for (int i = 0; i < 4; ++i) {
    aoff[i] = (wm * 64 + i * 16 + lc) * 40 + lq * 8;
    boff[i] = (wn * 64 + i * 16 + lc) * 40 + lq * 8;
  }

  float4 a0 = *(const float4*)(Ag + 0), a1 = *(const float4*)(Ag + 4),
         a2 = *(const float4*)(Ag + 8), a3 = *(const float4*)(Ag + 12);
  uint4 b0 = *(const uint4*)(Bg + 0), b1 = *(const uint4*)(Bg + 8);

  for (int kb = 0; kb < 16; ++kb) {
    __syncthreads();
    uint4 p0 = {bfpack2(a0.x, a0.y), bfpack2(a0.z, a0.w),
                bfpack2(a1.x, a1.y), bfpack2(a1.z, a1.w)};
    uint4 p1 = {bfpack2(a2.x, a2.y), bfpack2(a2.z, a2.w),
                bfpack2(a3.x, a3.y), bfpack2(a3.z, a3.w)};
    *(uint4*)(At + sr * 40 + sk) = p0;
    *(uint4*)(At + sr * 40 + sk + 8) = p1;
    *(uint4*)(Bt + sr * 40 + sk) = b0;
    *(uint4*)(Bt + sr * 40 + sk + 8) = b1;
    __syncthreads();
    if (kb < 15) {
      const float* ag = Ag + (kb + 1) * 32;
      const ushort* bg = Bg + (kb + 1) * 32;
      a0 = *(const float4*)(ag + 0); a1 = *(const float4*)(ag + 4);
      a2 = *(const float4*)(ag + 8); a3 = *(const float4*)(ag + 12);
      b0 = *(const uint4*)(bg + 0); b1 = *(const uint4*)(bg + 8);
    }
    s16x8 af[4], bf[4];
#pragma unroll
    for (int mi = 0; mi < 4; ++mi) af[mi] = *(const s16x8*)(At + aoff[mi]);
#pragma unroll
    for (int ni = 0; ni < 4; ++ni) bf[ni] = *(const s16x8*)(Bt + boff[ni]);
#pragma unroll
    for (int mi = 0; mi < 4; ++mi)
#pragma unroll
      for (int ni = 0; ni < 4; ++ni)
        acc[mi][ni] = __builtin_amdgcn_mfma_f32_16x16x32_bf16(
            af[mi], bf[ni], acc[mi][ni], 0, 0, 0);
  }

  float pbv[4], swv[4];
#pragma unroll
  for (int ni = 0; ni < 4; ++ni) {
    int n = bn * 128 + wn * 64 + ni * 16 + lc;
    pbv[ni] = pb[n];
    swv[ni] = sw[n];
  }
#pragma unroll
  for (int mi = 0; mi < 4; ++mi) {
#pragma unroll
    for (int r = 0; r < 4; ++r) {
      float s = 0.f;
#pragma unroll
      for (int ni = 0; ni < 4; ++ni) {
        float x = acc[mi][ni][r] + pbv[ni];
        float e = __expf(2.f * x);
        float th = 1.f - 2.f / (e + 1.f);
        s = fmaf(th, swv[ni], s);
      }
      s += __shfl_xor(s, 1);
      s += __shfl_xor(s, 2);
      s += __shfl_xor(s, 4);
      s += __shfl_xor(s, 8);
      if (lc == 0) {
        int m = bm * 128 + wm * 64 + mi * 16 + lq * 4 + r;
        atomicAdd(&logits[m], s);
      }
    }
  }
}

// ---------------------------------------------------------------------------
// K2: actT[b][c][l] = relu(act[b][l][c]);  dinv[b][l] = 1/max(sum_c relu, 1)
// ---------------------------------------------------------------------------
__global__ void k2_transpose(const float* __restrict__ act,
                             float* __restrict__ actT,
                             float* __restrict__ dinv) {
  __shared__ float t64[64][65];
  const int b = blockIdx.x >> 6;
  const int l0 = (blockIdx.x & 63) * 64;
  const int tid = threadIdx.x;
#pragma unroll
  for (int i = 0; i < 16; ++i) {
    int e = tid + i * 256;
    int l = e >> 6, c = e & 63;
    float v = act[((size_t)(b * Ll + l0 + l)) * Cc + c];
    t64[l][c] = fmaxf(v, 0.f);
  }
  __syncthreads();
  if (tid < 64) {
    float s = 0.f;
#pragma unroll 8
    for (int c = 0; c < 64; ++c) s += t64[tid][c];
    dinv[b * Ll + l0 + tid] = 1.0f / fmaxf(s, 1.0f);
  }
#pragma unroll
  for (int i = 0; i < 16; ++i) {
    int e = tid + i * 256;
    int c = e >> 6, lq = e & 63;
    actT[((size_t)(b * Cc + c)) * Ll + l0 + lq] = t64[lq][c];
  }
}

// ---------------------------------------------------------------------------
// K3: per (b,c) row softmax over L -> weights output (fp32) + bf16 copy.
// ---------------------------------------------------------------------------
__global__ void k3_softmax(const float* __restrict__ actT,
                           const float* __restrict__ logits,
                           float* __restrict__ wout,
                           ushort* __restrict__ wb16,
                           int* __restrict__ hasany) {
  __shared__ float rmax[4], rcnt[4], rsum[4];
  const int bid = blockIdx.x;  // b*64+c
  const int b = bid >> 6;
  const int tid = threadIdx.x;
  const float* arow = actT + (size_t)bid * Ll;

  float xs[16];
  float lmax = NEGV, fcnt = 0.f;
#pragma unroll
  for (int i = 0; i < 16; ++i) {
    int l = tid + i * 256;
    float a = arow[l];
    float x;
    if (a > 0.f) {
      x = logits[b * Ll + l] + log1pf(a);
      fcnt += 1.f;
    } else {
      x = NEGV;
    }
    xs[i] = x;
    lmax = fmaxf(lmax, x);
  }
#pragma unroll
  for (int m = 32; m >= 1; m >>= 1) {
    lmax = fmaxf(lmax, __shfl_xor(lmax, m));
    fcnt += __shfl_xor(fcnt, m);
  }
  if ((tid & 63) == 0) { rmax[tid >> 6] = lmax; rcnt[tid >> 6] = fcnt; }
  __syncthreads();
  float m4 = fmaxf(fmaxf(rmax[0], rmax[1]), fmaxf(rmax[2], rmax[3]));
  float call = rcnt[0] + rcnt[1] + rcnt[2] + rcnt[3];

  float lsum = 0.f;
#pragma unroll
  for (int i = 0; i < 16; ++i) {
    float e = expf(xs[i] - m4);
    xs[i] = e;
    lsum += e;
  }
#pragma unroll
  for (int m = 32; m >= 1; m >>= 1) lsum += __shfl_xor(lsum, m);
  if ((tid & 63) == 0) rsum[tid >> 6] = lsum;
  __syncthreads();
  float s = rsum[0] + rsum[1] + rsum[2] + rsum[3];
  int any = call > 0.5f;
  float inv = any ? 1.0f / s : 0.f;
#pragma unroll
  for (int i = 0; i < 16; ++i) {
    float wv = xs[i] * inv;
    wout[(size_t)bid * Ll + tid + i * 256] = wv;
    wb16[(size_t)bid * Ll + tid + i * 256] = f2bf(wv);
  }
  if (tid == 0) hasany[bid] = any;
}

// ---------------------------------------------------------------------------
// K5: bf16 MFMA partial GEMM: pbuf[kz][b][c][h] = sum_{l in slice} w*hid.
// Grid (8 b, 4 nt, 16 kz), 256 thr (4 waves). Block tile M=64,N=128,K=256.
// Wave w covers n = nt*128 + w*32 .. +31 (2 frags); all 4 m-tiles.
// A-frags: direct global 16B loads from wb16 (natural [c][l] layout).
// B-frags: per-lane gather of 8 l-values for its h-column, packed to bf16.
// No LDS, no atomics.
// ---------------------------------------------------------------------------
__global__ __launch_bounds__(256) void k5_mfma(
    const ushort* __restrict__ wb16, const float* __restrict__ hid,
    float* __restrict__ pbuf) {
  const int b = blockIdx.x, nt = blockIdx.y, kz = blockIdx.z;
  const int tid = threadIdx.x;
  const int w = tid >> 6, lane = tid & 63;
  const int lc = lane & 15, lq = lane >> 4;
  const int h0 = nt * 128 + w * 32;

  f32x4 acc[4][2];
#pragma unroll
  for (int mi = 0; mi < 4; ++mi)
#pragma unroll
    for (int ni = 0; ni < 2; ++ni) acc[mi][ni] = (f32x4){0.f, 0.f, 0.f, 0.f};

  const ushort* Abase =
      wb16 + (size_t)b * Cc * Ll + (size_t)lc * Ll + kz * 256 + lq * 8;
  const float* Bbase =
      hid + ((size_t)(b * Ll + kz * 256 + lq * 8)) * Hh + h0 + lc;

  for (int kb = 0; kb < 8; ++kb) {
    s16x8 af[4];
#pragma unroll
    for (int mi = 0; mi < 4; ++mi)
      af[mi] = *(const s16x8*)(Abase + (size_t)mi * 16 * Ll + kb * 32);
    s16x8 bf[2];
#pragma unroll
    for (int ni = 0; ni < 2; ++ni) {
      const float* bp = Bbase + (size_t)kb * 32 * Hh + ni * 16;
      uint u0 = bfpack2(bp[0 * Hh], bp[1 * Hh]);
      uint u1 = bfpack2(bp[2 * Hh], bp[3 * Hh]);
      uint u2 = bfpack2(bp[4 * Hh], bp[5 * Hh]);
      uint u3 = bfpack2(bp[6 * Hh], bp[7 * Hh]);
      union { uint4 u4; s16x8 s; } cv;
      cv.u4 = (uint4){u0, u1, u2, u3};
      bf[ni] = cv.s;
    }
#pragma unroll
    for (int mi = 0; mi < 4; ++mi)
#pragma unroll
      for (int ni = 0; ni < 2; ++ni)
        acc[mi][ni] = __builtin_amdgcn_mfma_f32_16x16x32_bf16(
            af[mi], bf[ni], acc[mi][ni], 0, 0, 0);
  }

  const size_t obase = ((size_t)(kz * Bb + b)) * Cc * Hh;
#pragma unroll
  for (int mi = 0; mi < 4; ++mi)
#pragma unroll
    for (int ni = 0; ni < 2; ++ni)
#pragma unroll
      for (int r = 0; r < 4; ++r)
        pbuf[obase + (size_t)(mi * 16 + lq * 4 + r) * Hh + h0 + ni * 16 + lc] =
            acc[mi][ni][r];
}

// ---------------------------------------------------------------------------
// K6: reduce 16 partials + fallback substitution.
// ---------------------------------------------------------------------------
__global__ void k6_reduce(const float* __restrict__ pbuf,
                          const int* __restrict__ hasany,
                          const float* __restrict__ hid,
                          float* __restrict__ cctx) {
  int idx = blockIdx.x * 256 + threadIdx.x;  // 0..262143
  float s = 0.f;
#pragma unroll
  for (int z = 0; z < 16; ++z) s += pbuf[(size_t)z * 262144 + idx];
  int bc = idx >> 9, b = idx >> 15, h = idx & 511;
  cctx[idx] = hasany[bc] ? s : hid[((size_t)(b * Ll + Ll - 1)) * Hh + h];
}

// ---------------------------------------------------------------------------
// K7: attended = mask ? (mix @ cctx) * gate : hidden
// ---------------------------------------------------------------------------
__global__ __launch_bounds__(256, 2) void k7_out(
    const float* __restrict__ hid, const float* __restrict__ act,
    const float* __restrict__ dinv, const float* __restrict__ cctx,
    const int* __restrict__ mask, const int* __restrict__ cnt,
    const int* __restrict__ cmax, float* __restrict__ out) {
  __shared__ float mix[32 * 68];
  __shared__ float gateb[32];
  __shared__ int maskb[32];
  const int b = blockIdx.x;
  const int l0 = blockIdx.y * 32;
  const int tid = threadIdx.x;
  const float maxcf = fmaxf((float)cmax[b], 1.0f);

#pragma unroll
  for (int i = 0; i < 2; ++i) {
    int q = tid + i * 256;
    int t = q >> 4, cq = q & 15;
    float4 a4 = *(const float4*)(act + ((size_t)(b * Ll + l0 + t)) * Cc + cq * 4);
    float dv = dinv[b * Ll + l0 + t];
    a4.x = fmaxf(a4.x, 0.f) * dv;
    a4.y = fmaxf(a4.y, 0.f) * dv;
    a4.z = fmaxf(a4.z, 0.f) * dv;
    a4.w = fmaxf(a4.w, 0.f) * dv;
    *(float4*)(mix + t * 68 + cq * 4) = a4;
  }
  if (tid < 32) {
    int l = l0 + tid;
    maskb[tid] = mask[b * Ll + l];
    gateb[tid] = 1.0f + (float)cnt[b * Ll + l] / maxcf;
  }
  __syncthreads();

  const int tt = tid >> 6;
  const int h = (tid & 63) * 8;
  float acc[8][8];
#pragma unroll
  for (int t = 0; t < 8; ++t)
#pragma unroll
    for (int u = 0; u < 8; ++u) acc[t][u] = 0.f;

#pragma unroll 4
  for (int c = 0; c < 64; ++c) {
    float4 cA = *(const float4*)(cctx + ((size_t)(b * Cc + c)) * Hh + h);
    float4 cB = *(const float4*)(cctx + ((size_t)(b * Cc + c)) * Hh + h + 4);
    float cv[8] = {cA.x, cA.y, cA.z, cA.w, cB.x, cB.y, cB.z, cB.w};
#pragma unroll
    for (int t = 0; t < 8; ++t) {
      float mv = mix[(tt * 8 + t) * 68 + c];
#pragma unroll
      for (int u = 0; u < 8; ++u) acc[t][u] = fmaf(mv, cv[u], acc[t][u]);
    }
  }
#pragma unroll
  for (int t = 0; t < 8; ++t) {
    int tok = tt * 8 + t;
    size_t off = ((size_t)(b * Ll + l0 + tok)) * Hh + h;
    float4 o1, o2;
    if (maskb[tok]) {
      float g = gateb[tok];
      o1 = make_float4(acc[t][0] * g, acc[t][1] * g, acc[t][2] * g, acc[t][3] * g);
      o2 = make_float4(acc[t][4] * g, acc[t][5] * g, acc[t][6] * g, acc[t][7] * g);
    } else {
      o1 = *(const float4*)(hid + off);
      o2 = *(const float4*)(hid + off + 4);
    }
    *(float4*)(out + off) = o1;
    *(float4*)(out + off + 4) = o2;
  }
}

// ---------------------------------------------------------------------------
extern "C" void kernel_launch(void* const* d_in, const int* in_sizes, int n_in,
                              void* d_out, int out_size, void* d_ws,
                              size_t ws_size, hipStream_t stream) {
  const float* hid = (const float*)d_in[0];
  const int* mask = (const int*)d_in[1];
  const int* cnt = (const int*)d_in[2];
  const float* act = (const float*)d_in[3];
  const float* pw = (const float*)d_in[4];
  const float* pb = (const float*)d_in[5];
  const float* sw = (const float*)d_in[6];
  const float* sb = (const float*)d_in[7];

  float* out_att = (float*)d_out;                 // (B,L,H)
  float* out_w = out_att + (size_t)Bb * Ll * Hh;  // (B,C,L)

  float* ws = (float*)d_ws;
  float* cctx = ws;                               // 262144 f
  int* cmaxi = (int*)(ws + 262144);               // 8 i
  float* logits = ws + 262152;                    // 32768 f
  float* actT = ws + 294920;                      // 2097152 f
  float* dinv = ws + 2392072;                     // 32768 f
  int* hasany = (int*)(ws + 2424840);             // 512 i
  ushort* pwT = (ushort*)(ws + 2425352);          // 262144 bf16
  ushort* wb16 = (ushort*)(ws + 2556424);         // 2097152 bf16
  float* pbuf = ws + 3605000;                     // 4194304 f (16 MB)

  hipMemsetAsync(cmaxi, 0, 8 * sizeof(int), stream);

  k_init<<<128, 256, 0, stream>>>(cnt, sb, logits, cmaxi);
  kT_pw<<<64, 256, 0, stream>>>(pw, pwT);
  k0_gemm<<<dim3(256, 4), 256, 0, stream>>>(hid, pwT, pb, sw, logits);
  k2_transpose<<<512, 256, 0, stream>>>(act, actT, dinv);
  k3_softmax<<<512, 256, 0, stream>>>(actT, logits, out_w, wb16, hasany);
  k5_mfma<<<dim3(8, 4, 16), 256, 0, stream>>>(wb16, hid, pbuf);
  k6_reduce<<<1024, 256, 0, stream>>>(pbuf, hasany, hid, cctx);
  k7_out<<<dim3(8, 128), 256, 0, stream>>>(hid, act, dinv, cctx, mask, cnt,
                                           cmaxi, out_att);
}